// Round 6
// baseline (414.033 us; speedup 1.0000x reference)
//
#include <hip/hip_runtime.h>

// R13 DIAGNOSTIC ROUND (v2 — fixed probe_lean OOB: linear index ran 5x past
// the 268 MB buffer; now outer sweep loop re-reads the same range).
// The gemv (~100 us) has never been visible in the top-5 rocprof rows
// (fills are ~160 us), so every bottleneck theory since R5 was inferred from
// a single scalar. Six structures (R5-R8, R11, R12) all land at 2.9-3.0 TB/s
// effective B-stream. This round buys the counters: R11's kernel runs
// unchanged (correct output, best-known), then two LOADS-ONLY probes each
// stream B 5x (1.34 GB) so they exceed the 160 us visibility threshold:
//   probe_matched: R11's shape (512x512, burst-16, ~80 VGPR, 16 waves/CU)
//   probe_lean:    max headroom (2048x256, LB(256,8), ~45 VGPR, 32 waves/CU)
// Pre-committed reads: both ~3 TB/s -> funnel is structural, R11 = roofline.
// lean fast + matched slow -> occupancy is the lever (redo R10 cleanly).
// both fast -> consume-structure serializes; restructure consume.

#define TPB   512
#define ROWS  2
#define TILES 16
#define CROWS (ROWS * TILES)   // 32 rows per block

typedef int   ivec4 __attribute__((ext_vector_type(4)));
typedef float fvec2 __attribute__((ext_vector_type(2)));

// ---------------------------------------------------------------- R11 gemv --
__global__ __launch_bounds__(TPB, 4) void gemv_w4pipe(
    const float4* __restrict__ A4,
    const ivec4*  __restrict__ B,
    const fvec2*  __restrict__ SZ,
    float* __restrict__ out,
    int N)
{
    const int t    = threadIdx.x;
    const int row0 = blockIdx.x * CROWS;
    const int g0   = t >> 2;

    __shared__ fvec2 sz_s[2][ROWS * 256];
    __shared__ float red[2][ROWS][TPB / 64];

    float a[2][8];
    float sA[2];
#pragma unroll
    for (int j = 0; j < 2; ++j) {
        const int i = t + 512 * j;
        const float4 x = A4[2 * i];
        const float4 y = A4[2 * i + 1];
        a[j][0] = x.x; a[j][1] = x.y; a[j][2] = x.z; a[j][3] = x.w;
        a[j][4] = y.x; a[j][5] = y.y; a[j][6] = y.z; a[j][7] = y.w;
        sA[j] = ((x.x + x.y) + (x.z + x.w)) + ((y.x + y.y) + (y.z + y.w));
    }

    ivec4 bufA[ROWS][2], bufB[ROWS][2];
    fvec2 szrA, szrB;

    auto issue = [&](int T, ivec4 (&buf)[ROWS][2], fvec2& szr) {
        const int rt = row0 + T * ROWS;
        szr = __builtin_nontemporal_load(&SZ[(size_t)rt * 256 + t]);
        const ivec4* Bp = B + (size_t)rt * 1024 + t;
#pragma unroll
        for (int r = 0; r < ROWS; ++r)
#pragma unroll
            for (int j = 0; j < 2; ++j)
                buf[r][j] = __builtin_nontemporal_load(&Bp[r * 1024 + 512 * j]);
    };

    auto consume = [&](const ivec4 (&buf)[ROWS][2], const fvec2* szl,
                       float (&redb)[ROWS][TPB / 64]) {
        float acc[ROWS];
#pragma unroll
        for (int r = 0; r < ROWS; ++r) acc[r] = 0.0f;
#pragma unroll
        for (int r = 0; r < ROWS; ++r) {
#pragma unroll
            for (int j = 0; j < 2; ++j) {
                const fvec2 sz = szl[r * 256 + g0 + 128 * j];
                const int b0 = buf[r][j][0], b1 = buf[r][j][1];
                const int b2 = buf[r][j][2], b3 = buf[r][j][3];
                float dot = 0.0f;
                dot = fmaf(a[j][0], (float)(b0 & 0xF),        dot);
                dot = fmaf(a[j][1], (float)((b0 >> 4) & 0xF), dot);
                dot = fmaf(a[j][2], (float)(b1 & 0xF),        dot);
                dot = fmaf(a[j][3], (float)((b1 >> 4) & 0xF), dot);
                dot = fmaf(a[j][4], (float)(b2 & 0xF),        dot);
                dot = fmaf(a[j][5], (float)((b2 >> 4) & 0xF), dot);
                dot = fmaf(a[j][6], (float)(b3 & 0xF),        dot);
                dot = fmaf(a[j][7], (float)((b3 >> 4) & 0xF), dot);
                acc[r] = fmaf(sz[0], dot, acc[r]);
                acc[r] = fmaf(fmaf(-8.0f, sz[0], sz[1]), sA[j], acc[r]);
            }
        }
        const int lane = t & 63;
        const int w    = t >> 6;
#pragma unroll
        for (int r = 0; r < ROWS; ++r) {
            float v = acc[r];
#pragma unroll
            for (int off = 32; off > 0; off >>= 1)
                v += __shfl_down(v, off, 64);
            if (lane == 0) redb[r][w] = v;
        }
    };

    auto store2 = [&](int T, const float (&redb)[ROWS][TPB / 64]) {
        if (t < ROWS) {
            const int n = row0 + T * ROWS + t;
            if (n < N) {
                float v = 0.0f;
#pragma unroll
                for (int w2 = 0; w2 < TPB / 64; ++w2) v += redb[t][w2];
                out[n] = v;
            }
        }
    };

    issue(0, bufA, szrA);
    sz_s[0][t] = szrA;
    __syncthreads();

    for (int TT = 0; TT < TILES; TT += 2) {
        if (TT + 1 < TILES) issue(TT + 1, bufB, szrB);
        consume(bufA, &sz_s[0][0], red[0]);
        if (TT + 1 < TILES) sz_s[1][t] = szrB;
        __syncthreads();
        store2(TT, red[0]);

        if (TT + 2 < TILES) issue(TT + 2, bufA, szrA);
        consume(bufB, &sz_s[1][0], red[1]);
        if (TT + 2 < TILES) sz_s[0][t] = szrA;
        __syncthreads();
        store2(TT + 1, red[1]);
    }
}

// ------------------------------------------------------------ probe_matched --
// R11's exact memory shape: 512 blocks x 512 thr, block owns a contiguous
// 512 KB region, burst of 16 ivec4/thread, ~80 VGPR -> 16 waves/CU.
// Streams B 5x = 1.34 GB (same addresses each sweep; nt so no L1 help).
__global__ __launch_bounds__(512, 4) void probe_matched(
    const ivec4* __restrict__ B)
{
    const int t = threadIdx.x;
    const ivec4* Bp = B + (size_t)blockIdx.x * 32768 + t;  // 32 rows * 1024
    int acc = 0;
    for (int s = 0; s < 5; ++s) {
        ivec4 r[16];
#pragma unroll
        for (int m = 0; m < 16; ++m)
            r[m] = __builtin_nontemporal_load(&Bp[512 * m]);   // max 7680+511 ok
#pragma unroll
        for (int m = 0; m < 16; ++m)
            acc += (r[m][0] + r[m][1]) + (r[m][2] + r[m][3]);
    }
    asm volatile("" :: "v"(acc));   // keep the whole stream live (rule #17)
}

// --------------------------------------------------------------- probe_lean --
// Max-headroom streaming shape: 2048 blocks x 256 thr, LB(256,8) -> <=64
// VGPR -> 32 waves/CU; chip-wide interleaved sweep (copy-kernel-like);
// 8-deep burst. 32 ivec4/thread/sweep covers B exactly; 5 sweeps = 1.34 GB.
__global__ __launch_bounds__(256, 8) void probe_lean(
    const ivec4* __restrict__ B)
{
    const size_t tid      = (size_t)blockIdx.x * 256 + threadIdx.x;
    const size_t nthreads = (size_t)2048 * 256;            // 524288
    int acc = 0;
    for (int s = 0; s < 5; ++s) {
        for (int i = 0; i < 32; i += 8) {                  // 32*524288 = |B|
            ivec4 r[8];
#pragma unroll
            for (int j = 0; j < 8; ++j)
                r[j] = __builtin_nontemporal_load(
                           &B[tid + (size_t)(i + j) * nthreads]);
#pragma unroll
            for (int j = 0; j < 8; ++j)
                acc += (r[j][0] + r[j][1]) + (r[j][2] + r[j][3]);
        }
    }
    asm volatile("" :: "v"(acc));
}

extern "C" void kernel_launch(void* const* d_in, const int* in_sizes, int n_in,
                              void* d_out, int out_size, void* d_ws, size_t ws_size,
                              hipStream_t stream) {
    const float4* A4 = (const float4*)d_in[0];   // f32[8192]
    const ivec4*  B  = (const ivec4*)d_in[1];    // int32[N, 4096]
    const fvec2*  SZ = (const fvec2*)d_in[2];    // f32[N, 256, 2]
    float* out = (float*)d_out;                  // f32[N]

    const int N = out_size;                      // 16384
    gemv_w4pipe<<<N / CROWS, TPB, 0, stream>>>(A4, B, SZ, out, N);
    // diagnostic probes: read-only on B, write nothing, run after the real op
    probe_matched<<<512, 512, 0, stream>>>(B);
    probe_lean<<<2048, 256, 0, stream>>>(B);
}